// Round 10
// baseline (157.919 us; speedup 1.0000x reference)
//
#include <hip/hip_runtime.h>
#include <hip/hip_bf16.h>

// MixingBlock round 10: 1024 threads / 16 waves per block, TB=64, grid=256.
// Same math & LDS as round 9; per-wave register state halved so 4 waves/SIMD
// fit (1024-thr block forces <=128 regs). Two-phase LN reduce (16->8 slots).

typedef __attribute__((ext_vector_type(8))) short short8;
typedef __attribute__((ext_vector_type(4))) short short4v;
typedef __attribute__((ext_vector_type(4))) float f32x4;
typedef unsigned short u16;

#define B_   8
#define N_   2048
#define EPS_ 1e-6f
#define TB   64

// ws element offsets (bf16)
#define OFF_CS 0        // wt_cs [256][1152]  (k*384 col blocks: [s_win|vdot])
#define OFF_V  294912   // wt_v  [128][768]   (k*256: [vwin(128)|cross(128)])
#define OFF_G  393216   // wt_g  [128][768]   (k*256: s_rhat weights)
#define OFF_SS 491520   // wt_ss [256][256]
#define OFF_SV 557056   // wt_sv [128][128]

#define MFMA(a,b,c) __builtin_amdgcn_mfma_f32_16x16x32_bf16((a),(b),(c),0,0,0)

__device__ __forceinline__ u16 f2b(float v){ __hip_bfloat16 h=__float2bfloat16(v); return *(u16*)&h; }

// ---------------- weight prep: transpose + remap + f32->bf16 ----------------
__global__ __launch_bounds__(256) void prep_weights(
    const float* __restrict__ Wcs, const float* __restrict__ Wcv,
    const float* __restrict__ Wss, const float* __restrict__ Wsv,
    u16* __restrict__ ws)
{
    const int bid = blockIdx.x;
    const float* src; int N, r0, ld, c0; u16* dst; int tile;
    if (bid < 288)      { src=Wcs; N=256; r0=0; dst=ws+OFF_CS; ld=1152; c0=0; tile=bid; }
    else if (bid < 336) { int k=(bid-288)/16; tile=(bid-288)%16;
                          src=Wcv; N=128; r0=k*512;     dst=ws+OFF_V; ld=768; c0=k*256; }
    else if (bid < 432) { int k=(bid-336)/32; tile=(bid-336)%32;
                          src=Wcv; N=128; r0=k*512+128; dst=ws+OFF_G; ld=768; c0=k*256; }
    else if (bid < 480) { int k=(bid-432)/16; tile=(bid-432)%16;
                          src=Wcv; N=128; r0=k*512+384; dst=ws+OFF_V; ld=768; c0=k*256+128; }
    else if (bid < 544) { tile=bid-480; src=Wss; N=256; r0=0; dst=ws+OFF_SS; ld=256; c0=0; }
    else                { tile=bid-544; src=Wsv; N=128; r0=0; dst=ws+OFF_SV; ld=128; c0=0; }
    const int ntN = N >> 5;
    const int kt = (tile/ntN)*32, nn = (tile%ntN)*32;
    __shared__ float t[32][33];
    const int r = threadIdx.x >> 5, c = threadIdx.x & 31;
#pragma unroll
    for (int i = 0; i < 4; ++i)
        t[r+8*i][c] = src[(size_t)(r0+kt+r+8*i)*N + nn+c];
    __syncthreads();
#pragma unroll
    for (int i = 0; i < 4; ++i)
        dst[(size_t)(nn+r+8*i)*ld + c0+kt+c] = f2b(t[c][r+8*i]);
}

// LN reduce, 16 waves: butterfly over 16 lanes, two-phase cross-wave into
// red[64][8] (wg=0 writes, wg=1 adds), then finalize. vsp = vec scale for
// this wave's token pair (mm = 2*wg + b).
__device__ __forceinline__ void ln_reduce16(
    float p1[4][4], float p2[4][4], float pv[4][4], f32x4* red,
    int lm, int lq4, int wh, int wg,
    float mu[4][4], float ss[4][4], float vsp[2][4])
{
    __syncthreads();
#pragma unroll
    for (int m2 = 1; m2 < 16; m2 <<= 1)
#pragma unroll
        for (int m = 0; m < 4; ++m)
#pragma unroll
            for (int q = 0; q < 4; ++q) {
                p1[m][q] += __shfl_xor(p1[m][q], m2);
                p2[m][q] += __shfl_xor(p2[m][q], m2);
                pv[m][q] += __shfl_xor(pv[m][q], m2);
            }
    if (lm == 0 && wg == 0)
#pragma unroll
        for (int m = 0; m < 4; ++m)
#pragma unroll
            for (int q = 0; q < 4; ++q) {
                f32x4 r = {p1[m][q], p2[m][q], pv[m][q], 0.f};
                red[(m*16+lq4+q)*8 + wh] = r;
            }
    __syncthreads();
    if (lm == 0 && wg == 1)
#pragma unroll
        for (int m = 0; m < 4; ++m)
#pragma unroll
            for (int q = 0; q < 4; ++q) {
                f32x4 r = red[(m*16+lq4+q)*8 + wh];
                r.x += p1[m][q]; r.y += p2[m][q]; r.z += pv[m][q];
                red[(m*16+lq4+q)*8 + wh] = r;
            }
    __syncthreads();
#pragma unroll
    for (int m = 0; m < 4; ++m)
#pragma unroll
        for (int q = 0; q < 4; ++q) {
            const int t = m*16 + lq4 + q;
            f32x4 rs = red[t*8+0];
#pragma unroll
            for (int i = 1; i < 8; ++i) rs += red[t*8+i];
            const float mm_ = rs.x * (1.f/256.f);
            mu[m][q] = mm_;
            ss[m][q] = rsqrtf(rs.y*(1.f/256.f) - mm_*mm_ + EPS_);
            const float vv_ = rsqrtf(rs.z*(1.f/128.f) + EPS_);
            if (m == 2*wg)     vsp[0][q] = vv_;
            if (m == 2*wg + 1) vsp[1][q] = vv_;
        }
}

__global__ __launch_bounds__(1024) void mixing_main(
    const float* __restrict__ x_s, const float* __restrict__ x_v,
    const float* __restrict__ coords, const u16* __restrict__ wt,
    float* __restrict__ out)
{
    // fs [64][392]u16 @0 | fv [192][264]u16 @50176 | rhp [64][3][4]f32
    // @151552 | red [64][8]f32x4 @154624. Aliases: hsb [64][264]@0,
    // hvb [192][136]@50176, xvL [64*384]f32 @50176.
    __shared__ __align__(16) char smem[162816];
    u16*   fs  = (u16*)smem;
    u16*   fv  = (u16*)(smem + 50176);
    u16*   hsb = (u16*)smem;
    u16*   hvb = (u16*)(smem + 50176);
    float* xvL = (float*)(smem + 50176);
    float* rhp = (float*)(smem + 151552);
    f32x4* red = (f32x4*)(smem + 154624);

    const int tid = threadIdx.x;
    const int w   = tid >> 6;           // 0..15
    const int wh  = w & 7, wg = w >> 3; // col-octant, token-half
    const int l   = tid & 63;
    const int lm  = l & 15, lk8 = (l >> 4) << 3, lq4 = (l >> 4) << 2;
    const int gt0 = blockIdx.x * TB;
    const int n0  = gt0 & (N_ - 1);
    const int seq0 = gt0 - n0;
    const size_t ZV0 = (size_t)B_ * N_ * 256;

    // rhat [64 t][3 k]
    if (tid < 192) {
        const int t = tid / 3, k = tid - 3 * (tid / 3);
        const int jn = n0 + t + k - 1;
        const int jc = jn < 0 ? 0 : (jn > N_-1 ? N_-1 : jn);
        const float* cj = coords + (size_t)(seq0 + jc) * 3;
        const float* c0p = coords + (size_t)(gt0 + t) * 3;
        const float d0 = cj[0]-c0p[0], d1 = cj[1]-c0p[1], d2 = cj[2]-c0p[2];
        const float dn = sqrtf(d0*d0 + d1*d1 + d2*d2);
        const float inv = dn > 1e-6f ? 1.f/dn : 0.f;
        rhp[(t*3+k)*4+0] = d0*inv; rhp[(t*3+k)*4+1] = d1*inv; rhp[(t*3+k)*4+2] = d2*inv;
    }
    __syncthreads();

    const f32x4 fz = {0.f,0.f,0.f,0.f};
    f32x4 acc_s[4];     // [m], single col-frag (2wh+wg)
    f32x4 accv[6];      // j = d*2 + b, token frag mm = 2wg+b, col frag wh
#pragma unroll
    for (int m = 0; m < 4; ++m) acc_s[m] = fz;
#pragma unroll
    for (int j = 0; j < 6; ++j) accv[j] = fz;

    const int bt = tid >> 4;   // token 0..63
    const int bx = tid & 15;

#pragma unroll 1
    for (int k = 0; k < 3; ++k) {
        const int jn = n0 + bt + k - 1;
        const bool valid = (unsigned)jn < (unsigned)N_;
        const size_t j = (size_t)seq0 + (valid ? jn : 0);
        // ---- s_win: 16 channels/thread
        {
            const int c0 = bx * 16;
            float v[16];
            if (valid) {
                const float4* sp = (const float4*)(x_s + j*256 + c0);
#pragma unroll
                for (int i = 0; i < 4; ++i) {
                    const float4 f = sp[i];
                    v[4*i]=f.x; v[4*i+1]=f.y; v[4*i+2]=f.z; v[4*i+3]=f.w;
                }
            } else {
#pragma unroll
                for (int i = 0; i < 16; ++i) v[i] = 0.f;
            }
            short8 p0, p1;
#pragma unroll
            for (int i = 0; i < 8; ++i) { p0[i]=(short)f2b(v[i]); p1[i]=(short)f2b(v[8+i]); }
            *(short8*)(fs + bt*392 + c0)     = p0;
            *(short8*)(fs + bt*392 + c0 + 8) = p1;
        }
        // ---- x_v-derived: vdot / vwin / cross, 8 ch/thread in 2 halves
        {
            const int c0 = bx * 8;
            const float r0 = rhp[(bt*3+k)*4+0];
            const float r1 = rhp[(bt*3+k)*4+1];
            const float r2 = rhp[(bt*3+k)*4+2];
#pragma unroll
            for (int hh = 0; hh < 2; ++hh) {
                float vv[12];
                if (valid) {
                    const float4* vp = (const float4*)(x_v + ((size_t)j*128 + c0 + 4*hh)*3);
#pragma unroll
                    for (int i = 0; i < 3; ++i) {
                        const float4 f = vp[i];
                        vv[4*i]=f.x; vv[4*i+1]=f.y; vv[4*i+2]=f.z; vv[4*i+3]=f.w;
                    }
                } else {
#pragma unroll
                    for (int i = 0; i < 12; ++i) vv[i] = 0.f;
                }
                short4v dv, w0, w1, w2, x0, x1, x2;
#pragma unroll
                for (int m = 0; m < 4; ++m) {
                    const float a0 = vv[3*m], a1 = vv[3*m+1], a2 = vv[3*m+2];
                    dv[m] = (short)f2b(a0*r0 + a1*r1 + a2*r2);
                    w0[m] = (short)f2b(a0); w1[m] = (short)f2b(a1); w2[m] = (short)f2b(a2);
                    x0[m] = (short)f2b(a1*r2 - a2*r1);
                    x1[m] = (short)f2b(a2*r0 - a0*r2);
                    x2[m] = (short)f2b(a0*r1 - a1*r0);
                }
                const int cc = c0 + 4*hh;
                *(short4v*)(fs + bt*392 + 256 + cc)          = dv;
                *(short4v*)(fv + (0*64+bt)*264 + cc)         = w0;
                *(short4v*)(fv + (1*64+bt)*264 + cc)         = w1;
                *(short4v*)(fv + (2*64+bt)*264 + cc)         = w2;
                *(short4v*)(fv + (0*64+bt)*264 + 128 + cc)   = x0;
                *(short4v*)(fv + (1*64+bt)*264 + 128 + cc)   = x1;
                *(short4v*)(fv + (2*64+bt)*264 + 128 + cc)   = x2;
            }
        }
        __syncthreads();

        const u16* rowS = wt + OFF_CS + k*384 + (size_t)((2*wh+wg)*16+lm)*1152;
        const u16* rowG = wt + OFF_G  + k*256 + (size_t)(wh*16+lm)*768;
        const u16* rowV = wt + OFF_V  + k*256 + (size_t)(wh*16+lm)*768;

        // ---- scalar conv (K=384) + g (K=256, token-half split)
        f32x4 agc[2] = {fz, fz};
#pragma unroll
        for (int ks = 0; ks < 12; ++ks) {
            const int ko = ks*32 + lk8;
            const short8 b = *(const short8*)(rowS + ko);
            short8 a[4];
#pragma unroll
            for (int m = 0; m < 4; ++m)
                a[m] = *(const short8*)(fs + (m*16+lm)*392 + ko);
#pragma unroll
            for (int m = 0; m < 4; ++m)
                acc_s[m] = MFMA(a[m], b, acc_s[m]);
            if (ks < 8) {
                const short8 bg = *(const short8*)(rowG + ko);
                // a for tokens in this wave's half: m = 2wg, 2wg+1
                const short8 ag0 = *(const short8*)(fs + ((2*wg+0)*16+lm)*392 + ko);
                const short8 ag1 = *(const short8*)(fs + ((2*wg+1)*16+lm)*392 + ko);
                agc[0] = MFMA(ag0, bg, agc[0]);
                agc[1] = MFMA(ag1, bg, agc[1]);
            }
        }
        // ---- vec conv: 6 m-frags (3d x token-half) share each b
#pragma unroll
        for (int ks = 0; ks < 8; ++ks) {
            const int ko = ks*32 + lk8;
            const short8 bv = *(const short8*)(rowV + ko);
#pragma unroll
            for (int jj = 0; jj < 6; ++jj) {
                const int d = jj >> 1, bb = jj & 1;
                const short8 a = *(const short8*)(
                    fv + (d*64 + (2*wg+bb)*16 + lm)*264 + ko);
                accv[jj] = MFMA(a, bv, accv[jj]);
            }
        }
        // ---- fold g into accv
#pragma unroll
        for (int jj = 0; jj < 6; ++jj) {
            const int d = jj >> 1, bb = jj & 1;
#pragma unroll
            for (int q = 0; q < 4; ++q) {
                const int t = (2*wg+bb)*16 + lq4 + q;
                accv[jj][q] += agc[bb][q] * rhp[(t*3+k)*4+d];
            }
        }
        __syncthreads();
    }

    // ---- fan-in scales
    const float inv_fs = 0.029462783f;     // 1/sqrt(1152)
    const float inv_fv = 0.0255155136f;    // 1/sqrt(1536)
#pragma unroll
    for (int m = 0; m < 4; ++m)
#pragma unroll
        for (int q = 0; q < 4; ++q) acc_s[m][q] *= inv_fs;
#pragma unroll
    for (int jj = 0; jj < 6; ++jj)
#pragma unroll
        for (int q = 0; q < 4; ++q) accv[jj][q] *= inv_fv;

    // ---- LN1 partials
    float p1[4][4], p2[4][4], pv[4][4], mu[4][4], ss[4][4], vsp[2][4];
    {
        float s0[4], s1[4];
#pragma unroll
        for (int q = 0; q < 4; ++q) {
            s0[q] = accv[0][q]*accv[0][q] + accv[2][q]*accv[2][q] + accv[4][q]*accv[4][q];
            s1[q] = accv[1][q]*accv[1][q] + accv[3][q]*accv[3][q] + accv[5][q]*accv[5][q];
        }
#pragma unroll
        for (int m = 0; m < 4; ++m)
#pragma unroll
            for (int q = 0; q < 4; ++q) {
                const float x = acc_s[m][q];
                p1[m][q] = x; p2[m][q] = x*x;
                pv[m][q] = (m == 2*wg) ? s0[q] : ((m == 2*wg+1) ? s1[q] : 0.f);
            }
    }
    ln_reduce16(p1, p2, pv, red, lm, lq4, wh, wg, mu, ss, vsp);

    // apply LN1 + bf16 staging for SI
#pragma unroll
    for (int m = 0; m < 4; ++m)
#pragma unroll
        for (int q = 0; q < 4; ++q) {
            const float h = (acc_s[m][q] - mu[m][q]) * ss[m][q];
            acc_s[m][q] = h;
            hsb[(m*16+lq4+q)*264 + (2*wh+wg)*16 + lm] = f2b(h);
        }
#pragma unroll
    for (int jj = 0; jj < 6; ++jj) {
        const int d = jj >> 1, bb = jj & 1;
#pragma unroll
        for (int q = 0; q < 4; ++q) {
            const float h = accv[jj][q] * vsp[bb][q];
            accv[jj][q] = h;
            hvb[(d*64 + (2*wg+bb)*16 + lq4 + q)*136 + wh*16 + lm] = f2b(h);
        }
    }
    __syncthreads();

    // ---- SI GEMMs (scalar then vec; accumulators phase-local)
    {
        const u16* rowP = wt + OFF_SS + (size_t)((2*wh+wg)*16+lm)*256;
        f32x4 accs[4] = {fz, fz, fz, fz};
#pragma unroll
        for (int ks = 0; ks < 8; ++ks) {
            const int ko = ks*32 + lk8;
            const short8 c = *(const short8*)(rowP + ko);
#pragma unroll
            for (int m = 0; m < 4; ++m) {
                const short8 a = *(const short8*)(hsb + (m*16+lm)*264 + ko);
                accs[m] = MFMA(a, c, accs[m]);
            }
        }
#pragma unroll
        for (int m = 0; m < 4; ++m)
#pragma unroll
            for (int q = 0; q < 4; ++q) acc_s[m][q] += accs[m][q] * 0.0625f;
    }
    {
        const u16* rowQ = wt + OFF_SV + (size_t)(wh*16+lm)*128;
        f32x4 accw[6] = {fz, fz, fz, fz, fz, fz};
#pragma unroll
        for (int ks = 0; ks < 4; ++ks) {
            const int ko = ks*32 + lk8;
            const short8 c = *(const short8*)(rowQ + ko);
#pragma unroll
            for (int jj = 0; jj < 6; ++jj) {
                const int d = jj >> 1, bb = jj & 1;
                const short8 a = *(const short8*)(
                    hvb + (d*64 + (2*wg+bb)*16 + lm)*136 + ko);
                accw[jj] = MFMA(a, c, accw[jj]);
            }
        }
#pragma unroll
        for (int jj = 0; jj < 6; ++jj)
#pragma unroll
            for (int q = 0; q < 4; ++q) accv[jj][q] += accw[jj][q] * 0.08838834764f;
    }

    // ---- LN2 partials + early x_v residual loads
    {
        float s0[4], s1[4];
#pragma unroll
        for (int q = 0; q < 4; ++q) {
            s0[q] = accv[0][q]*accv[0][q] + accv[2][q]*accv[2][q] + accv[4][q]*accv[4][q];
            s1[q] = accv[1][q]*accv[1][q] + accv[3][q]*accv[3][q] + accv[5][q]*accv[5][q];
        }
#pragma unroll
        for (int m = 0; m < 4; ++m)
#pragma unroll
            for (int q = 0; q < 4; ++q) {
                const float x = acc_s[m][q];
                p1[m][q] = x; p2[m][q] = x*x;
                pv[m][q] = (m == 2*wg) ? s0[q] : ((m == 2*wg+1) ? s1[q] : 0.f);
            }
    }
    float4 xr[6];
    {
        const float4* xvsrc = (const float4*)(x_v + (size_t)gt0 * 384);
#pragma unroll
        for (int i = 0; i < 6; ++i) xr[i] = xvsrc[tid + i*1024];
    }
    ln_reduce16(p1, p2, pv, red, lm, lq4, wh, wg, mu, ss, vsp);  // entry barrier fences hvb reads
#pragma unroll
    for (int i = 0; i < 6; ++i) ((float4*)xvL)[tid + i*1024] = xr[i];
    __syncthreads();

    // ---- apply LN2 + residuals
#pragma unroll
    for (int m = 0; m < 4; ++m)
#pragma unroll
        for (int q = 0; q < 4; ++q)
            acc_s[m][q] = (acc_s[m][q] - mu[m][q]) * ss[m][q]
                + x_s[(size_t)(gt0 + m*16 + lq4 + q)*256 + (2*wh+wg)*16 + lm];
#pragma unroll
    for (int jj = 0; jj < 6; ++jj) {
        const int d = jj >> 1, bb = jj & 1;
#pragma unroll
        for (int q = 0; q < 4; ++q) {
            const int t = (2*wg+bb)*16 + lq4 + q;
            accv[jj][q] = accv[jj][q] * vsp[bb][q]
                + xvL[t*384 + (wh*16+lm)*3 + d];
        }
    }

    // ---- LN3
    {
        float s0[4], s1[4];
#pragma unroll
        for (int q = 0; q < 4; ++q) {
            s0[q] = accv[0][q]*accv[0][q] + accv[2][q]*accv[2][q] + accv[4][q]*accv[4][q];
            s1[q] = accv[1][q]*accv[1][q] + accv[3][q]*accv[3][q] + accv[5][q]*accv[5][q];
        }
#pragma unroll
        for (int m = 0; m < 4; ++m)
#pragma unroll
            for (int q = 0; q < 4; ++q) {
                const float x = acc_s[m][q];
                p1[m][q] = x; p2[m][q] = x*x;
                pv[m][q] = (m == 2*wg) ? s0[q] : ((m == 2*wg+1) ? s1[q] : 0.f);
            }
    }
    ln_reduce16(p1, p2, pv, red, lm, lq4, wh, wg, mu, ss, vsp);

    // z_s: direct store
#pragma unroll
    for (int m = 0; m < 4; ++m)
#pragma unroll
        for (int q = 0; q < 4; ++q)
            out[(size_t)(gt0 + m*16 + lq4 + q)*256 + (2*wh+wg)*16 + lm] =
                (acc_s[m][q] - mu[m][q]) * ss[m][q];
    // z_v: stage in LDS, then coalesced NT float4 copy
#pragma unroll
    for (int jj = 0; jj < 6; ++jj) {
        const int d = jj >> 1, bb = jj & 1;
#pragma unroll
        for (int q = 0; q < 4; ++q) {
            const int t = (2*wg+bb)*16 + lq4 + q;
            xvL[t*384 + (wh*16+lm)*3 + d] = accv[jj][q] * vsp[bb][q];
        }
    }
    __syncthreads();
    {
        f32x4* dst = (f32x4*)(out + ZV0 + (size_t)gt0 * 384);
        const f32x4* srcv = (const f32x4*)xvL;
#pragma unroll
        for (int i = 0; i < 6; ++i)
            __builtin_nontemporal_store(srcv[tid + i*1024], dst + tid + i*1024);
    }
}

extern "C" void kernel_launch(void* const* d_in, const int* in_sizes, int n_in,
                              void* d_out, int out_size, void* d_ws, size_t ws_size,
                              hipStream_t stream) {
    const float* x_s    = (const float*)d_in[0];
    const float* x_v    = (const float*)d_in[1];
    const float* coords = (const float*)d_in[2];
    const float* Wcs    = (const float*)d_in[3];
    const float* Wcv    = (const float*)d_in[4];
    const float* Wss    = (const float*)d_in[5];
    const float* Wsv    = (const float*)d_in[6];
    float* out = (float*)d_out;
    u16* ws = (u16*)d_ws;

    hipLaunchKernelGGL(prep_weights, dim3(560), dim3(256), 0, stream,
                       Wcs, Wcv, Wss, Wsv, ws);
    hipLaunchKernelGGL(mixing_main, dim3((B_ * N_) / TB), dim3(1024), 0, stream,
                       x_s, x_v, coords, ws, out);
}